// Round 1
// baseline (906.673 us; speedup 1.0000x reference)
//
#include <hip/hip_runtime.h>
#include <math.h>

#define B_ 1024
#define N_ 64
#define DIN 64
#define HID 128
#define HEADS 4
#define EPG 512                 // edges per graph (448 rand + 64 self loops)
#define VTOT (B_ * N_)          // 65536
#define ETOT (B_ * EPG)         // 524288
#define LN_EPS 1e-5f
#define NEG_SLOPE 0.2f

// ---------- helpers ----------
__device__ __forceinline__ float wave_sum(float v) {
#pragma unroll
    for (int o = 32; o > 0; o >>= 1) v += __shfl_xor(v, o);
    return v;
}

// order-preserving float<->uint encoding for atomicMax on possibly-negative floats
__device__ __forceinline__ unsigned fenc(float f) {
    unsigned u = __float_as_uint(f);
    return (u & 0x80000000u) ? ~u : (u | 0x80000000u);
}
__device__ __forceinline__ float fdec(unsigned u) {
    return (u & 0x80000000u) ? __uint_as_float(u & 0x7fffffffu)
                             : __uint_as_float(~u);
}

// ---------- K1: align Linear(64->128) + LayerNorm + sigmoid gate ----------
// block = 256 threads = 4 nodes; each node handled by one 64-lane wave.
__global__ __launch_bounds__(256) void k_align(
    const float* __restrict__ fv, const float* __restrict__ W,
    const float* __restrict__ bias, const float* __restrict__ gamma,
    const float* __restrict__ beta, const float* __restrict__ ml,
    float* __restrict__ x, float* __restrict__ gate_out)
{
    __shared__ float sfv[4][DIN];
    const int t = threadIdx.x;
    const int sub = t >> 6;
    const int lane = t & 63;
    const int v = blockIdx.x * 4 + sub;

    sfv[sub][lane] = fv[v * DIN + lane];
    __syncthreads();

    float a0 = 0.f, a1 = 0.f;
#pragma unroll 8
    for (int k = 0; k < DIN; ++k) {
        float f = sfv[sub][k];
        a0 += f * W[k * HID + lane];
        a1 += f * W[k * HID + 64 + lane];
    }
    a0 += bias[lane];
    a1 += bias[64 + lane];

    // LayerNorm across 128 values held 2-per-lane within the wave
    float mu = wave_sum(a0 + a1) * (1.f / HID);
    float c0 = a0 - mu, c1 = a1 - mu;
    float var = wave_sum(c0 * c0 + c1 * c1) * (1.f / HID);
    float rstd = rsqrtf(var + LN_EPS);
    float g = 1.f / (1.f + expf(-ml[v & 63]));

    x[v * HID + lane]      = (c0 * rstd * gamma[lane]      + beta[lane])      * g;
    x[v * HID + 64 + lane] = (c1 * rstd * gamma[64 + lane] + beta[64 + lane]) * g;

    if (blockIdx.x == 0 && t < N_) gate_out[t] = 1.f / (1.f + expf(-ml[t]));
}

// ---------- shared attention machinery (one head, one graph, block=256) ----------
// On entry sh[64][128] holds this head's h values (already __syncthreads'ed).
// On exit: s_alpha[e] = exp(score - segmax), s_den[d] = denom, CSR (s_off/s_list),
// s_src[e] = local src node. All synced.
__device__ void gat_head(
    const float (*sh)[HID],
    const int* __restrict__ e_src, const int* __restrict__ e_dst,
    short* s_src, short* s_dst, float* s_alpha,
    float* sa_src, float* sa_dst,
    unsigned* s_maxu, float* s_den,
    unsigned* s_cnt, unsigned* s_off, unsigned* s_cur, short* s_list,
    const float* __restrict__ att_src, const float* __restrict__ att_dst,
    int gbase)
{
    const int t = threadIdx.x;
    const int lane = t & 63, wid = t >> 6;

    // a_src[v], a_dst[v]: 64 nodes x 2 dots of length 128, wave-parallel over k
    float as0 = att_src[lane], as1 = att_src[64 + lane];
    float ad0 = att_dst[lane], ad1 = att_dst[64 + lane];
    for (int i = wid * 16; i < wid * 16 + 16; ++i) {
        float h0 = sh[i][lane], h1 = sh[i][64 + lane];
        float vs = wave_sum(h0 * as0 + h1 * as1);
        float vd = wave_sum(h0 * ad0 + h1 * ad1);
        if (lane == 0) { sa_src[i] = vs; sa_dst[i] = vd; }
    }
    if (t < 64) { s_maxu[t] = 0u; s_den[t] = 0.f; s_cnt[t] = 0u; }
    __syncthreads();

    // scores + segment max
#pragma unroll
    for (int e = t; e < EPG; e += 256) {
        int sv = e_src[e] - gbase;
        int dv = e_dst[e] - gbase;
        s_src[e] = (short)sv;
        s_dst[e] = (short)dv;
        float sc = sa_src[sv] + sa_dst[dv];
        sc = sc > 0.f ? sc : NEG_SLOPE * sc;
        s_alpha[e] = sc;
        atomicMax(&s_maxu[dv], fenc(sc));
    }
    __syncthreads();

    // exp + denom + per-dst counts
#pragma unroll
    for (int e = t; e < EPG; e += 256) {
        int dv = s_dst[e];
        float ex = expf(s_alpha[e] - fdec(s_maxu[dv]));
        s_alpha[e] = ex;
        atomicAdd(&s_den[dv], ex);
        atomicAdd(&s_cnt[dv], 1u);
    }
    __syncthreads();

    // CSR offsets (serial 64-scan is cheap)
    if (t == 0) {
        unsigned acc = 0;
        for (int v2 = 0; v2 < 64; ++v2) { s_off[v2] = acc; s_cur[v2] = acc; acc += s_cnt[v2]; }
        s_off[64] = acc;
    }
    __syncthreads();
#pragma unroll
    for (int e = t; e < EPG; e += 256) {
        unsigned p = atomicAdd(&s_cur[s_dst[e]], 1u);
        s_list[p] = (short)e;
    }
    __syncthreads();
}

// ---------- K2: GAT layer 1, fused GEMM(128->128 per head) + attention + ELU ----------
// grid = B*HEADS blocks; block (g,h) computes x1[g*64 .. , h*128 .. +128]
__global__ __launch_bounds__(256, 2) void k_gat1(
    const float* __restrict__ x, const float* __restrict__ W1,
    const float* __restrict__ att_src1, const float* __restrict__ att_dst1,
    const float* __restrict__ bias1, const int* __restrict__ edge_index,
    float* __restrict__ x1)
{
    __shared__ float sx[64][HID];
    __shared__ float sh[64][HID];
    __shared__ float s_alpha[EPG];
    __shared__ short s_src[EPG], s_dst[EPG], s_list[EPG];
    __shared__ float sa_src[64], sa_dst[64], s_den[64];
    __shared__ unsigned s_maxu[64], s_cnt[64], s_cur[64], s_off[65];

    const int bid = blockIdx.x;
    const int g = bid >> 2, h = bid & 3;
    const int hbase = h * HID;
    const int t = threadIdx.x;

    // load x tile [64][128]
    {
        const float4* src4 = (const float4*)(x + (size_t)g * 64 * HID);
        float4* dst4 = (float4*)&sx[0][0];
#pragma unroll
        for (int i = 0; i < 8; ++i) dst4[t + i * 256] = src4[t + i * 256];
    }
    __syncthreads();

    // GEMM: h[64][128] = sx @ W1[:, hbase:hbase+128]
    const int c0 = (t & 31) * 4;
    const int r0 = (t >> 5) * 8;
    float acc[8][4];
#pragma unroll
    for (int i = 0; i < 8; ++i)
#pragma unroll
        for (int c = 0; c < 4; ++c) acc[i][c] = 0.f;

    const float* Wp = W1 + hbase + c0;
#pragma unroll 4
    for (int k = 0; k < HID; k += 4) {
        float4 w0 = *(const float4*)&Wp[(k + 0) * (HEADS * HID)];
        float4 w1 = *(const float4*)&Wp[(k + 1) * (HEADS * HID)];
        float4 w2 = *(const float4*)&Wp[(k + 2) * (HEADS * HID)];
        float4 w3 = *(const float4*)&Wp[(k + 3) * (HEADS * HID)];
#pragma unroll
        for (int i = 0; i < 8; ++i) {
            float4 xv = *(const float4*)&sx[r0 + i][k];
            acc[i][0] += xv.x * w0.x + xv.y * w1.x + xv.z * w2.x + xv.w * w3.x;
            acc[i][1] += xv.x * w0.y + xv.y * w1.y + xv.z * w2.y + xv.w * w3.y;
            acc[i][2] += xv.x * w0.z + xv.y * w1.z + xv.z * w2.z + xv.w * w3.z;
            acc[i][3] += xv.x * w0.w + xv.y * w1.w + xv.z * w2.w + xv.w * w3.w;
        }
    }
#pragma unroll
    for (int i = 0; i < 8; ++i)
        *(float4*)&sh[r0 + i][c0] = make_float4(acc[i][0], acc[i][1], acc[i][2], acc[i][3]);
    __syncthreads();

    gat_head(sh, edge_index + (size_t)g * EPG, edge_index + ETOT + (size_t)g * EPG,
             s_src, s_dst, s_alpha, sa_src, sa_dst, s_maxu, s_den,
             s_cnt, s_off, s_cur, s_list,
             att_src1 + hbase, att_dst1 + hbase, g * 64);

    // aggregate per dst + bias + ELU + store
    const int f = t & 127;
    const float bsum = bias1[hbase + f];
    for (int d = (t >> 7); d < 64; d += 2) {
        float rden = 1.f / (s_den[d] + 1e-16f);
        float a = 0.f;
        for (unsigned ii = s_off[d]; ii < s_off[d + 1]; ++ii) {
            int e = s_list[ii];
            a += s_alpha[e] * sh[s_src[e]][f];
        }
        float o = a * rden + bsum;
        o = o > 0.f ? o : expm1f(o);   // ELU
        x1[((size_t)g * 64 + d) * (HEADS * HID) + hbase + f] = o;
    }
}

// ---------- K3: GAT layer 2 (512->128, 1 head) + mean pool ----------
// grid = B blocks; block g writes graph_embedding[g]
__global__ __launch_bounds__(256, 2) void k_gat2(
    const float* __restrict__ x1, const float* __restrict__ W2,
    const float* __restrict__ att_src2, const float* __restrict__ att_dst2,
    const float* __restrict__ bias2, const int* __restrict__ edge_index,
    float* __restrict__ out)
{
    __shared__ float schunk[64][HID];
    __shared__ float sh[64][HID];
    __shared__ float s_alpha[EPG];
    __shared__ short s_src[EPG], s_dst[EPG], s_list[EPG];
    __shared__ float sa_src[64], sa_dst[64], s_den[64];
    __shared__ unsigned s_maxu[64], s_cnt[64], s_cur[64], s_off[65];
    __shared__ float spool[2][HID];

    const int g = blockIdx.x;
    const int t = threadIdx.x;
    const int c0 = (t & 31) * 4;
    const int r0 = (t >> 5) * 8;

    float acc[8][4];
#pragma unroll
    for (int i = 0; i < 8; ++i)
#pragma unroll
        for (int c = 0; c < 4; ++c) acc[i][c] = 0.f;

    // h2[64][128] = x1_tile[64][512] @ W2, K staged in 4 chunks of 128
    for (int chunk = 0; chunk < 4; ++chunk) {
        __syncthreads();
        const float* src = x1 + ((size_t)g * 64) * (HEADS * HID) + chunk * HID;
#pragma unroll
        for (int i = 0; i < 8; ++i) {
            int idx = t + i * 256;          // 2048 float4s in the tile
            int r = idx >> 5, c4 = idx & 31;
            *(float4*)&schunk[r][c4 * 4] =
                *(const float4*)&src[(size_t)r * (HEADS * HID) + c4 * 4];
        }
        __syncthreads();
        const float* Wp = W2 + (size_t)chunk * HID * HID + c0;
#pragma unroll 4
        for (int k = 0; k < HID; k += 4) {
            float4 w0 = *(const float4*)&Wp[(k + 0) * HID];
            float4 w1 = *(const float4*)&Wp[(k + 1) * HID];
            float4 w2 = *(const float4*)&Wp[(k + 2) * HID];
            float4 w3 = *(const float4*)&Wp[(k + 3) * HID];
#pragma unroll
            for (int i = 0; i < 8; ++i) {
                float4 xv = *(const float4*)&schunk[r0 + i][k];
                acc[i][0] += xv.x * w0.x + xv.y * w1.x + xv.z * w2.x + xv.w * w3.x;
                acc[i][1] += xv.x * w0.y + xv.y * w1.y + xv.z * w2.y + xv.w * w3.y;
                acc[i][2] += xv.x * w0.z + xv.y * w1.z + xv.z * w2.z + xv.w * w3.z;
                acc[i][3] += xv.x * w0.w + xv.y * w1.w + xv.z * w2.w + xv.w * w3.w;
            }
        }
    }
#pragma unroll
    for (int i = 0; i < 8; ++i)
        *(float4*)&sh[r0 + i][c0] = make_float4(acc[i][0], acc[i][1], acc[i][2], acc[i][3]);
    __syncthreads();

    gat_head(sh, edge_index + (size_t)g * EPG, edge_index + ETOT + (size_t)g * EPG,
             s_src, s_dst, s_alpha, sa_src, sa_dst, s_maxu, s_den,
             s_cnt, s_off, s_cur, s_list,
             att_src2, att_dst2, g * 64);

    // aggregate + bias2, then mean-pool over the 64 nodes
    const int f = t & 127;
    const int half = t >> 7;
    const float bsum = bias2[f];
    float psum = 0.f;
    for (int d = half; d < 64; d += 2) {
        float rden = 1.f / (s_den[d] + 1e-16f);
        float a = 0.f;
        for (unsigned ii = s_off[d]; ii < s_off[d + 1]; ++ii) {
            int e = s_list[ii];
            a += s_alpha[e] * sh[s_src[e]][f];
        }
        psum += a * rden + bsum;
    }
    spool[half][f] = psum;
    __syncthreads();
    if (t < HID) out[(size_t)g * HID + t] = (spool[0][t] + spool[1][t]) * (1.f / 64.f);
}

// ---------- launch ----------
extern "C" void kernel_launch(void* const* d_in, const int* in_sizes, int n_in,
                              void* d_out, int out_size, void* d_ws, size_t ws_size,
                              hipStream_t stream)
{
    (void)in_sizes; (void)n_in; (void)out_size; (void)ws_size;
    const float* fv        = (const float*)d_in[0];
    const float* W_align   = (const float*)d_in[1];
    const float* b_align   = (const float*)d_in[2];
    const float* ln_gamma  = (const float*)d_in[3];
    const float* ln_beta   = (const float*)d_in[4];
    const float* mask_log  = (const float*)d_in[5];
    const float* W1        = (const float*)d_in[6];
    const float* att_src1  = (const float*)d_in[7];
    const float* att_dst1  = (const float*)d_in[8];
    const float* bias1     = (const float*)d_in[9];
    const float* W2        = (const float*)d_in[10];
    const float* att_src2  = (const float*)d_in[11];
    const float* att_dst2  = (const float*)d_in[12];
    const float* bias2     = (const float*)d_in[13];
    const int*   edge_idx  = (const int*)d_in[14];
    // d_in[15] batch_idx unused (layout is g*64+n by construction)

    float* out = (float*)d_out;                     // [B*HID] emb, then [64] gate
    float* x   = (float*)d_ws;                      // [VTOT*HID]
    float* x1  = x + (size_t)VTOT * HID;            // [VTOT*512]

    k_align<<<VTOT / 4, 256, 0, stream>>>(fv, W_align, b_align, ln_gamma, ln_beta,
                                          mask_log, x, out + (size_t)B_ * HID);
    k_gat1<<<B_ * HEADS, 256, 0, stream>>>(x, W1, att_src1, att_dst1, bias1,
                                           edge_idx, x1);
    k_gat2<<<B_, 256, 0, stream>>>(x1, W2, att_src2, att_dst2, bias2,
                                   edge_idx, out);
}